// Round 1
// baseline (1583.545 us; speedup 1.0000x reference)
//
#include <hip/hip_runtime.h>
#include <hip/hip_bf16.h>

#define N_NODES 100000
#define D 128
#define E_EDGES 800000

// ---------------------------------------------------------------------------
// Kernel 1: edge scatter. One wave (64 lanes) per edge; lane i handles 2
// contiguous floats (float2) of the 128-wide feature row. Forward: feat[src]
// accumulated into sum_fwd[dst]; backward: feat[dst] into sum_bwd[src].
// Degrees counted by lanes 0/1.
// ---------------------------------------------------------------------------
__global__ __launch_bounds__(256) void edge_scatter_kernel(
    const float* __restrict__ feat,
    const int* __restrict__ src,
    const int* __restrict__ dst,
    float* __restrict__ sum_fwd,
    float* __restrict__ sum_bwd,
    float* __restrict__ deg_fwd,
    float* __restrict__ deg_bwd,
    int E)
{
    const int lane   = threadIdx.x & 63;
    const int wave   = (blockIdx.x * blockDim.x + threadIdx.x) >> 6;
    const int nwaves = (gridDim.x * blockDim.x) >> 6;

    for (int e = wave; e < E; e += nwaves) {
        const int s = src[e];
        const int d = dst[e];

        const float2 fs = *reinterpret_cast<const float2*>(&feat[(size_t)s * D + lane * 2]);
        const float2 fd = *reinterpret_cast<const float2*>(&feat[(size_t)d * D + lane * 2]);

        float* sf = &sum_fwd[(size_t)d * D + lane * 2];
        float* sb = &sum_bwd[(size_t)s * D + lane * 2];

        unsafeAtomicAdd(sf + 0, fs.x);
        unsafeAtomicAdd(sf + 1, fs.y);
        unsafeAtomicAdd(sb + 0, fd.x);
        unsafeAtomicAdd(sb + 1, fd.y);

        if (lane == 0)      unsafeAtomicAdd(&deg_fwd[d], 1.0f);
        else if (lane == 1) unsafeAtomicAdd(&deg_bwd[s], 1.0f);
    }
}

// ---------------------------------------------------------------------------
// Kernel 2: fused mean + concat + GEMM(384->128) + ReLU.
// Block = 256 threads computes a 32-row x 128-col output tile.
// K is chunked by 32; both the h-chunk (means computed on the fly) and the
// W-chunk are staged in LDS, k-major, with strides that are 16B-aligned so
// the compute loop does two ds_read_b128 per k (one broadcast h4, one
// contiguous w4) feeding 16 v_fmac_f32.
// ---------------------------------------------------------------------------
#define RPB 32          // rows per block
#define KC  32          // k-chunk
#define HSTR (RPB + 4)  // 36 floats: keeps float4 reads 16B-aligned
#define WSTR (D + 4)    // 132 floats: keeps float4 reads 16B-aligned

__global__ __launch_bounds__(256) void sage_gemm_kernel(
    const float* __restrict__ feat,
    const float* __restrict__ W,        // [128][384] row-major
    const float* __restrict__ sum_fwd,
    const float* __restrict__ sum_bwd,
    const float* __restrict__ deg_fwd,
    const float* __restrict__ deg_bwd,
    float* __restrict__ out)            // [N][128]
{
    __shared__ float hch[KC * HSTR];    // [kk][r]
    __shared__ float wch[KC * WSTR];    // [kk][o]
    __shared__ float invf[RPB];
    __shared__ float invb[RPB];

    const int t = threadIdx.x;
    const int block_row = blockIdx.x * RPB;   // N = 100000 = 3125 * 32 exactly

    if (t < RPB) {
        invf[t] = 1.0f / fmaxf(deg_fwd[block_row + t], 1.0f);
    } else if (t < 2 * RPB) {
        invb[t - RPB] = 1.0f / fmaxf(deg_bwd[block_row + (t - RPB)], 1.0f);
    }
    __syncthreads();

    const int oc = (t & 31) * 4;   // output-column group (0..124)
    const int rr = (t >> 5) * 4;   // row group (0..28)

    float acc[4][4] = {{0.f}};

    for (int k0 = 0; k0 < 3 * D; k0 += KC) {
        // ---- stage h chunk: KC x RPB values, means computed inline ----
        for (int idx = t; idx < KC * RPB; idx += 256) {
            const int kk = idx & (KC - 1);
            const int r  = idx >> 5;
            const int k  = k0 + kk;
            const size_t node = (size_t)(block_row + r);
            float v;
            if (k < D)            v = feat[node * D + k];
            else if (k < 2 * D)   v = sum_fwd[node * D + (k - D)] * invf[r];
            else                  v = sum_bwd[node * D + (k - 2 * D)] * invb[r];
            hch[kk * HSTR + r] = v;
        }
        // ---- stage W chunk: D x KC values ----
        for (int idx = t; idx < D * KC; idx += 256) {
            const int kk = idx & (KC - 1);
            const int o  = idx >> 5;
            wch[kk * WSTR + o] = W[(size_t)o * (3 * D) + k0 + kk];
        }
        __syncthreads();

        for (int kk = 0; kk < KC; ++kk) {
            const float4 w4 = *reinterpret_cast<const float4*>(&wch[kk * WSTR + oc]);
            const float4 h4 = *reinterpret_cast<const float4*>(&hch[kk * HSTR + rr]);
            const float wv[4] = {w4.x, w4.y, w4.z, w4.w};
            const float hv[4] = {h4.x, h4.y, h4.z, h4.w};
#pragma unroll
            for (int i = 0; i < 4; ++i)
#pragma unroll
                for (int j = 0; j < 4; ++j)
                    acc[i][j] += hv[i] * wv[j];
        }
        __syncthreads();
    }

#pragma unroll
    for (int i = 0; i < 4; ++i) {
        float4 v;
        v.x = fmaxf(acc[i][0], 0.0f);
        v.y = fmaxf(acc[i][1], 0.0f);
        v.z = fmaxf(acc[i][2], 0.0f);
        v.w = fmaxf(acc[i][3], 0.0f);
        *reinterpret_cast<float4*>(&out[(size_t)(block_row + rr + i) * D + oc]) = v;
    }
}

// ---------------------------------------------------------------------------
extern "C" void kernel_launch(void* const* d_in, const int* in_sizes, int n_in,
                              void* d_out, int out_size, void* d_ws, size_t ws_size,
                              hipStream_t stream) {
    const float* feat = (const float*)d_in[0];          // [N][128]
    const float* W    = (const float*)d_in[1];          // [128][384]
    const int*   ei   = (const int*)d_in[2];            // [2][E]
    float*       out  = (float*)d_out;                  // [N][128]

    const int E = in_sizes[2] / 2;                      // 800000
    const int N = in_sizes[0] / D;                      // 100000
    const int* src = ei;
    const int* dst = ei + E;

    // workspace layout (floats): sum_fwd[N*D] | sum_bwd[N*D] | deg_fwd[N] | deg_bwd[N]
    float* sum_fwd = (float*)d_ws;
    float* sum_bwd = sum_fwd + (size_t)N * D;
    float* deg_fwd = sum_bwd + (size_t)N * D;
    float* deg_bwd = deg_fwd + N;

    const size_t ws_used = ((size_t)2 * N * D + 2 * (size_t)N) * sizeof(float);
    hipMemsetAsync(d_ws, 0, ws_used, stream);

    edge_scatter_kernel<<<4096, 256, 0, stream>>>(feat, src, dst,
                                                  sum_fwd, sum_bwd,
                                                  deg_fwd, deg_bwd, E);

    sage_gemm_kernel<<<N / RPB, 256, 0, stream>>>(feat, W,
                                                  sum_fwd, sum_bwd,
                                                  deg_fwd, deg_bwd, out);
}

// Round 2
// 473.763 us; speedup vs baseline: 3.3425x; 3.3425x over previous
//
#include <hip/hip_runtime.h>
#include <hip/hip_bf16.h>

#define D 128
#define CHUNK 1024   // elements per scan block (256 thr x 4)

// ---------------------------------------------------------------------------
// Phase A: CSR build.
//   cnt[2N]: in-degree (fwd, node g=dst) and out-degree (bwd, g=N+src)
//   off[2N+1]: exclusive scan of cnt (concatenated, so csr is one 2E array)
//   csr[2E]: neighbor node id per segment slot
// ---------------------------------------------------------------------------
__global__ __launch_bounds__(256) void hist_kernel(
    const int* __restrict__ src, const int* __restrict__ dst,
    int* __restrict__ cnt, int E, int N)
{
    int i = blockIdx.x * blockDim.x + threadIdx.x;
    int stride = gridDim.x * blockDim.x;
    for (int e = i; e < E; e += stride) {
        atomicAdd(&cnt[dst[e]], 1);
        atomicAdd(&cnt[N + src[e]], 1);
    }
}

__global__ __launch_bounds__(256) void scan1_kernel(
    const int* __restrict__ cnt, int* __restrict__ blk, int n2)
{
    __shared__ int red[256];
    const int b = blockIdx.x, t = threadIdx.x;
    const int base = b * CHUNK + t * 4;
    int s = 0;
    if (base + 3 < n2) {
        int4 v = *reinterpret_cast<const int4*>(&cnt[base]);
        s = v.x + v.y + v.z + v.w;
    } else {
        for (int j = 0; j < 4; ++j) { int idx = base + j; if (idx < n2) s += cnt[idx]; }
    }
    red[t] = s; __syncthreads();
    for (int o = 128; o > 0; o >>= 1) { if (t < o) red[t] += red[t + o]; __syncthreads(); }
    if (t == 0) blk[b] = red[0];
}

__global__ __launch_bounds__(256) void scan2_kernel(int* __restrict__ blk, int NB)
{
    __shared__ int sh[256];
    const int t = threadIdx.x;
    sh[t] = (t < NB) ? blk[t] : 0;
    __syncthreads();
    for (int o = 1; o < 256; o <<= 1) {
        int v = (t >= o) ? sh[t - o] : 0;
        __syncthreads();
        sh[t] += v;
        __syncthreads();
    }
    if (t < NB) blk[t] = (t > 0) ? sh[t - 1] : 0;   // exclusive
}

__global__ __launch_bounds__(256) void scan3_kernel(
    const int* __restrict__ cnt, const int* __restrict__ blk,
    int* __restrict__ off, int n2, int total)
{
    __shared__ int sh[256];
    const int b = blockIdx.x, t = threadIdx.x;
    const int base = b * CHUNK + t * 4;
    int v[4]; int s = 0;
    for (int j = 0; j < 4; ++j) { int idx = base + j; v[j] = (idx < n2) ? cnt[idx] : 0; s += v[j]; }
    sh[t] = s; __syncthreads();
    for (int o = 1; o < 256; o <<= 1) {
        int x = (t >= o) ? sh[t - o] : 0;
        __syncthreads();
        sh[t] += x;
        __syncthreads();
    }
    int excl = blk[b] + ((t > 0) ? sh[t - 1] : 0);
    for (int j = 0; j < 4; ++j) {
        int idx = base + j;
        if (idx < n2) off[idx] = excl;
        excl += v[j];
    }
    if (b == 0 && t == 0) off[n2] = total;
}

__global__ __launch_bounds__(256) void scatter_ids_kernel(
    const int* __restrict__ src, const int* __restrict__ dst,
    const int* __restrict__ off, int* __restrict__ cur, int* __restrict__ csr,
    int E, int N)
{
    int i = blockIdx.x * blockDim.x + threadIdx.x;
    int stride = gridDim.x * blockDim.x;
    for (int e = i; e < E; e += stride) {
        const int s = src[e], d = dst[e];
        int p = off[d] + atomicAdd(&cur[d], 1);
        csr[p] = s;
        int p2 = off[N + s] + atomicAdd(&cur[N + s], 1);
        csr[p2] = d;
    }
}

// ---------------------------------------------------------------------------
// Phase B: gather means. One wave per segment (2N segments). Lane i owns
// float2 columns [2i, 2i+1]. Reads are 512 B/row (coalesced), feat is
// L3-resident; each mean row written exactly once. No float atomics.
// ---------------------------------------------------------------------------
__global__ __launch_bounds__(256) void gather_mean_kernel(
    const float* __restrict__ feat, const int* __restrict__ off,
    const int* __restrict__ csr, float* __restrict__ mean, int n2)
{
    const int wave = (blockIdx.x * blockDim.x + threadIdx.x) >> 6;
    const int lane = threadIdx.x & 63;
    if (wave >= n2) return;

    const int beg = off[wave], end = off[wave + 1];
    const int c = lane * 2;
    float ax = 0.f, ay = 0.f;

    int e = beg;
    for (; e + 1 < end; e += 2) {            // unroll-2 for load ILP
        const int n0 = csr[e], n1 = csr[e + 1];
        const float2 a = *reinterpret_cast<const float2*>(&feat[(size_t)n0 * D + c]);
        const float2 b = *reinterpret_cast<const float2*>(&feat[(size_t)n1 * D + c]);
        ax += a.x + b.x; ay += a.y + b.y;
    }
    if (e < end) {
        const int n0 = csr[e];
        const float2 a = *reinterpret_cast<const float2*>(&feat[(size_t)n0 * D + c]);
        ax += a.x; ay += a.y;
    }

    const int deg = end - beg;
    const float inv = 1.0f / (float)((deg > 1) ? deg : 1);
    float2 r; r.x = ax * inv; r.y = ay * inv;
    *reinterpret_cast<float2*>(&mean[(size_t)wave * D + c]) = r;
}

// ---------------------------------------------------------------------------
// Phase C: fused concat + GEMM(384->128) + ReLU (unchanged structure).
// ---------------------------------------------------------------------------
#define RPB 32
#define KC  32
#define HSTR (RPB + 4)
#define WSTR (D + 4)

__global__ __launch_bounds__(256) void sage_gemm_kernel(
    const float* __restrict__ feat,
    const float* __restrict__ W,
    const float* __restrict__ mean,   // [2N][D]: rows [0,N)=fwd, [N,2N)=bwd
    float* __restrict__ out, int N)
{
    __shared__ float hch[KC * HSTR];
    __shared__ float wch[KC * WSTR];

    const int t = threadIdx.x;
    const int block_row = blockIdx.x * RPB;

    const int oc = (t & 31) * 4;
    const int rr = (t >> 5) * 4;

    float acc[4][4] = {{0.f}};

    for (int k0 = 0; k0 < 3 * D; k0 += KC) {
        for (int idx = t; idx < KC * RPB; idx += 256) {
            const int kk = idx & (KC - 1);
            const int r  = idx >> 5;
            const int k  = k0 + kk;
            const size_t node = (size_t)(block_row + r);
            float v;
            if (k < D)            v = feat[node * D + k];
            else if (k < 2 * D)   v = mean[node * D + (k - D)];
            else                  v = mean[((size_t)N + node) * D + (k - 2 * D)];
            hch[kk * HSTR + r] = v;
        }
        for (int idx = t; idx < D * KC; idx += 256) {
            const int kk = idx & (KC - 1);
            const int o  = idx >> 5;
            wch[kk * WSTR + o] = W[(size_t)o * (3 * D) + k0 + kk];
        }
        __syncthreads();

        for (int kk = 0; kk < KC; ++kk) {
            const float4 w4 = *reinterpret_cast<const float4*>(&wch[kk * WSTR + oc]);
            const float4 h4 = *reinterpret_cast<const float4*>(&hch[kk * HSTR + rr]);
            const float wv[4] = {w4.x, w4.y, w4.z, w4.w};
            const float hv[4] = {h4.x, h4.y, h4.z, h4.w};
#pragma unroll
            for (int i = 0; i < 4; ++i)
#pragma unroll
                for (int j = 0; j < 4; ++j)
                    acc[i][j] += hv[i] * wv[j];
        }
        __syncthreads();
    }

#pragma unroll
    for (int i = 0; i < 4; ++i) {
        float4 v;
        v.x = fmaxf(acc[i][0], 0.0f);
        v.y = fmaxf(acc[i][1], 0.0f);
        v.z = fmaxf(acc[i][2], 0.0f);
        v.w = fmaxf(acc[i][3], 0.0f);
        *reinterpret_cast<float4*>(&out[(size_t)(block_row + rr + i) * D + oc]) = v;
    }
}

// ---------------------------------------------------------------------------
extern "C" void kernel_launch(void* const* d_in, const int* in_sizes, int n_in,
                              void* d_out, int out_size, void* d_ws, size_t ws_size,
                              hipStream_t stream) {
    const float* feat = (const float*)d_in[0];
    const float* W    = (const float*)d_in[1];
    const int*   ei   = (const int*)d_in[2];
    float*       out  = (float*)d_out;

    const int E = in_sizes[2] / 2;           // 800000
    const int N = in_sizes[0] / D;           // 100000
    const int n2 = 2 * N;
    const int* src = ei;
    const int* dst = ei + E;

    // ws layout (4B units):
    // cnt[n2] | cur[n2] | off[n2+4 pad] | blk[256] | csr[2E] | mean[n2*D] floats
    int* cnt = (int*)d_ws;
    int* cur = cnt + n2;
    int* off = cur + n2;
    int* blk = off + (n2 + 4);               // pad keeps mean 16B-aligned
    int* csr = blk + 256;
    float* mean = (float*)(csr + 2 * E);

    // zero cnt + cur only (1.6 MB)
    hipMemsetAsync(cnt, 0, (size_t)2 * n2 * sizeof(int), stream);

    const int NB = (n2 + CHUNK - 1) / CHUNK; // 196 for N=100000

    hist_kernel<<<2048, 256, 0, stream>>>(src, dst, cnt, E, N);
    scan1_kernel<<<NB, 256, 0, stream>>>(cnt, blk, n2);
    scan2_kernel<<<1, 256, 0, stream>>>(blk, NB);
    scan3_kernel<<<NB, 256, 0, stream>>>(cnt, blk, off, n2, 2 * E);
    scatter_ids_kernel<<<2048, 256, 0, stream>>>(src, dst, off, cur, csr, E, N);

    const int gather_blocks = (n2 * 64 + 255) / 256;  // one wave per segment
    gather_mean_kernel<<<gather_blocks, 256, 0, stream>>>(feat, off, csr, mean, n2);

    sage_gemm_kernel<<<N / RPB, 256, 0, stream>>>(feat, W, mean, out, N);
}

// Round 3
// 356.954 us; speedup vs baseline: 4.4363x; 1.3272x over previous
//
#include <hip/hip_runtime.h>
#include <hip/hip_bf16.h>

#define D 128
#define CHUNK 1024   // elements per scan block (256 thr x 4)

typedef __attribute__((ext_vector_type(8))) short bf16x8;
typedef __attribute__((ext_vector_type(4))) float f32x4;

// ---- bf16 helpers (bit-level, RNE via __float2bfloat16) --------------------
__device__ inline float bflo(unsigned u) { return __uint_as_float(u << 16); }
__device__ inline float bfhi(unsigned u) { return __uint_as_float(u & 0xffff0000u); }
__device__ inline unsigned short f2bf(float f) {
    __hip_bfloat16 h = __float2bfloat16(f);
    return *reinterpret_cast<unsigned short*>(&h);
}
__device__ inline unsigned pack2bf(float lo, float hi) {
    return (unsigned)f2bf(lo) | ((unsigned)f2bf(hi) << 16);
}

// ---------------------------------------------------------------------------
// fp32 -> bf16 conversion (vectorized: float4 in, 4x bf16 out)
// ---------------------------------------------------------------------------
__global__ __launch_bounds__(256) void tobf16_kernel(
    const float* __restrict__ x, unsigned short* __restrict__ y, int n4)
{
    int i = blockIdx.x * blockDim.x + threadIdx.x;
    int stride = gridDim.x * blockDim.x;
    for (; i < n4; i += stride) {
        float4 v = *reinterpret_cast<const float4*>(&x[(size_t)i * 4]);
        uint2 o;
        o.x = pack2bf(v.x, v.y);
        o.y = pack2bf(v.z, v.w);
        *reinterpret_cast<uint2*>(&y[(size_t)i * 4]) = o;
    }
}

// ---------------------------------------------------------------------------
// Phase A: CSR build (unchanged).
// ---------------------------------------------------------------------------
__global__ __launch_bounds__(256) void hist_kernel(
    const int* __restrict__ src, const int* __restrict__ dst,
    int* __restrict__ cnt, int E, int N)
{
    int i = blockIdx.x * blockDim.x + threadIdx.x;
    int stride = gridDim.x * blockDim.x;
    for (int e = i; e < E; e += stride) {
        atomicAdd(&cnt[dst[e]], 1);
        atomicAdd(&cnt[N + src[e]], 1);
    }
}

__global__ __launch_bounds__(256) void scan1_kernel(
    const int* __restrict__ cnt, int* __restrict__ blk, int n2)
{
    __shared__ int red[256];
    const int b = blockIdx.x, t = threadIdx.x;
    const int base = b * CHUNK + t * 4;
    int s = 0;
    if (base + 3 < n2) {
        int4 v = *reinterpret_cast<const int4*>(&cnt[base]);
        s = v.x + v.y + v.z + v.w;
    } else {
        for (int j = 0; j < 4; ++j) { int idx = base + j; if (idx < n2) s += cnt[idx]; }
    }
    red[t] = s; __syncthreads();
    for (int o = 128; o > 0; o >>= 1) { if (t < o) red[t] += red[t + o]; __syncthreads(); }
    if (t == 0) blk[b] = red[0];
}

__global__ __launch_bounds__(256) void scan2_kernel(int* __restrict__ blk, int NB)
{
    __shared__ int sh[256];
    const int t = threadIdx.x;
    sh[t] = (t < NB) ? blk[t] : 0;
    __syncthreads();
    for (int o = 1; o < 256; o <<= 1) {
        int v = (t >= o) ? sh[t - o] : 0;
        __syncthreads();
        sh[t] += v;
        __syncthreads();
    }
    if (t < NB) blk[t] = (t > 0) ? sh[t - 1] : 0;   // exclusive
}

__global__ __launch_bounds__(256) void scan3_kernel(
    const int* __restrict__ cnt, const int* __restrict__ blk,
    int* __restrict__ off, int n2, int total)
{
    __shared__ int sh[256];
    const int b = blockIdx.x, t = threadIdx.x;
    const int base = b * CHUNK + t * 4;
    int v[4]; int s = 0;
    for (int j = 0; j < 4; ++j) { int idx = base + j; v[j] = (idx < n2) ? cnt[idx] : 0; s += v[j]; }
    sh[t] = s; __syncthreads();
    for (int o = 1; o < 256; o <<= 1) {
        int x = (t >= o) ? sh[t - o] : 0;
        __syncthreads();
        sh[t] += x;
        __syncthreads();
    }
    int excl = blk[b] + ((t > 0) ? sh[t - 1] : 0);
    for (int j = 0; j < 4; ++j) {
        int idx = base + j;
        if (idx < n2) off[idx] = excl;
        excl += v[j];
    }
    if (b == 0 && t == 0) off[n2] = total;
}

__global__ __launch_bounds__(256) void scatter_ids_kernel(
    const int* __restrict__ src, const int* __restrict__ dst,
    const int* __restrict__ off, int* __restrict__ cur, int* __restrict__ csr,
    int E, int N)
{
    int i = blockIdx.x * blockDim.x + threadIdx.x;
    int stride = gridDim.x * blockDim.x;
    for (int e = i; e < E; e += stride) {
        const int s = src[e], d = dst[e];
        int p = off[d] + atomicAdd(&cur[d], 1);
        csr[p] = s;
        int p2 = off[N + s] + atomicAdd(&cur[N + s], 1);
        csr[p2] = d;
    }
}

// ---------------------------------------------------------------------------
// Phase B: gather means in bf16. 16 lanes per segment; lane l owns bf16
// columns [8l, 8l+8) (one 16B load per neighbor row). fp32 accumulate,
// bf16 output. 4 segments per wave -> 4x the memory-level parallelism of
// the wave-per-segment version.
// ---------------------------------------------------------------------------
__global__ __launch_bounds__(256) void gather_mean_kernel(
    const unsigned short* __restrict__ featb, const int* __restrict__ off,
    const int* __restrict__ csr, unsigned short* __restrict__ meanb, int n2)
{
    const int tid = blockIdx.x * 256 + threadIdx.x;
    const int seg = tid >> 4;
    const int l = tid & 15;
    if (seg >= n2) return;

    const int beg = off[seg], end = off[seg + 1];
    float a0=0,a1=0,a2=0,a3=0,a4=0,a5=0,a6=0,a7=0;

    int e = beg;
    for (; e + 1 < end; e += 2) {
        const int n0 = csr[e], n1 = csr[e + 1];
        const uint4 v0 = *reinterpret_cast<const uint4*>(featb + (size_t)n0 * D + l * 8);
        const uint4 v1 = *reinterpret_cast<const uint4*>(featb + (size_t)n1 * D + l * 8);
        a0 += bflo(v0.x) + bflo(v1.x); a1 += bfhi(v0.x) + bfhi(v1.x);
        a2 += bflo(v0.y) + bflo(v1.y); a3 += bfhi(v0.y) + bfhi(v1.y);
        a4 += bflo(v0.z) + bflo(v1.z); a5 += bfhi(v0.z) + bfhi(v1.z);
        a6 += bflo(v0.w) + bflo(v1.w); a7 += bfhi(v0.w) + bfhi(v1.w);
    }
    if (e < end) {
        const int n0 = csr[e];
        const uint4 v0 = *reinterpret_cast<const uint4*>(featb + (size_t)n0 * D + l * 8);
        a0 += bflo(v0.x); a1 += bfhi(v0.x);
        a2 += bflo(v0.y); a3 += bfhi(v0.y);
        a4 += bflo(v0.z); a5 += bfhi(v0.z);
        a6 += bflo(v0.w); a7 += bfhi(v0.w);
    }

    const int deg = end - beg;
    const float inv = 1.0f / (float)((deg > 1) ? deg : 1);
    uint4 o;
    o.x = pack2bf(a0 * inv, a1 * inv);
    o.y = pack2bf(a2 * inv, a3 * inv);
    o.z = pack2bf(a4 * inv, a5 * inv);
    o.w = pack2bf(a6 * inv, a7 * inv);
    *reinterpret_cast<uint4*>(meanb + (size_t)seg * D + l * 8) = o;
}

// ---------------------------------------------------------------------------
// Phase C: bf16 MFMA GEMM. out = h @ W^T, h = [featb | meanb_fwd | meanb_bwd].
// Block = 256 thr = 4 waves; wave handles 16 rows x 128 cols: 8 accumulator
// tiles of 16x16, K = 384 in 12 steps of 32. No LDS: a/b fragments are 16B
// global loads (W 98KB bf16 -> L2-resident; h rows read once).
// A-frag: row = lane&15, k = (lane>>4)*8 + i.  B-frag: col = lane&15, same k.
// C/D:    col = lane&15, row = (lane>>4)*4 + i  (m89-verified layout).
// ---------------------------------------------------------------------------
__global__ __launch_bounds__(256) void mfma_gemm_kernel(
    const unsigned short* __restrict__ featb,
    const unsigned short* __restrict__ meanb,
    const unsigned short* __restrict__ Wb,      // [128][384] bf16
    float* __restrict__ out, int N)
{
    const int t = threadIdx.x;
    const int wv = t >> 6;
    const int lane = t & 63;
    const int r = lane & 15;
    const int kb = (lane >> 4) * 8;

    const int row0 = blockIdx.x * 64 + wv * 16;
    const int row = row0 + r;
    const int rowc = (row < N) ? row : (N - 1);   // clamp loads on last block

    f32x4 acc[8];
#pragma unroll
    for (int n = 0; n < 8; ++n) acc[n] = (f32x4){0.f, 0.f, 0.f, 0.f};

    const unsigned short* h0 = featb + (size_t)rowc * D;
    const unsigned short* h1 = meanb + (size_t)rowc * D;
    const unsigned short* h2 = meanb + ((size_t)N + rowc) * D;

#pragma unroll
    for (int k0 = 0; k0 < 384; k0 += 32) {
        const unsigned short* hs = (k0 < 128) ? h0 : (k0 < 256) ? h1 : h2;
        const int ko = (k0 & 127) + kb;
        const bf16x8 a = *reinterpret_cast<const bf16x8*>(hs + ko);
#pragma unroll
        for (int n = 0; n < 8; ++n) {
            const int c = n * 16 + r;
            const bf16x8 b = *reinterpret_cast<const bf16x8*>(Wb + (size_t)c * 384 + k0 + kb);
            acc[n] = __builtin_amdgcn_mfma_f32_16x16x32_bf16(a, b, acc[n], 0, 0, 0);
        }
    }

    const int ro = row0 + (lane >> 4) * 4;
#pragma unroll
    for (int n = 0; n < 8; ++n) {
        const int c = n * 16 + r;
#pragma unroll
        for (int i = 0; i < 4; ++i) {
            const int rr2 = ro + i;
            if (rr2 < N) out[(size_t)rr2 * D + c] = fmaxf(acc[n][i], 0.0f);
        }
    }
}

// ---------------------------------------------------------------------------
extern "C" void kernel_launch(void* const* d_in, const int* in_sizes, int n_in,
                              void* d_out, int out_size, void* d_ws, size_t ws_size,
                              hipStream_t stream) {
    const float* feat = (const float*)d_in[0];
    const float* W    = (const float*)d_in[1];
    const int*   ei   = (const int*)d_in[2];
    float*       out  = (float*)d_out;

    const int E = in_sizes[2] / 2;           // 800000
    const int N = in_sizes[0] / D;           // 100000
    const int n2 = 2 * N;
    const int* src = ei;
    const int* dst = ei + E;

    // ws layout (4B units then 2B units, all 16B-aligned):
    // cnt[n2] | cur[n2] | off[n2+4] | blk[256] | csr[2E] |
    // featb[N*D] u16 | Wb[128*384] u16 | meanb[n2*D] u16
    int* cnt = (int*)d_ws;
    int* cur = cnt + n2;
    int* off = cur + n2;
    int* blk = off + (n2 + 4);
    int* csr = blk + 256;
    unsigned short* featb = (unsigned short*)(csr + 2 * E);
    unsigned short* Wb    = featb + (size_t)N * D;
    unsigned short* meanb = Wb + 128 * 384;

    hipMemsetAsync(cnt, 0, (size_t)2 * n2 * sizeof(int), stream);

    const int NB = (n2 + CHUNK - 1) / CHUNK; // 196

    tobf16_kernel<<<2048, 256, 0, stream>>>(feat, featb, N * D / 4);
    tobf16_kernel<<<48, 256, 0, stream>>>(W, Wb, 128 * 384 / 4);

    hist_kernel<<<2048, 256, 0, stream>>>(src, dst, cnt, E, N);
    scan1_kernel<<<NB, 256, 0, stream>>>(cnt, blk, n2);
    scan2_kernel<<<1, 256, 0, stream>>>(blk, NB);
    scan3_kernel<<<NB, 256, 0, stream>>>(cnt, blk, off, n2, 2 * E);
    scatter_ids_kernel<<<2048, 256, 0, stream>>>(src, dst, off, cur, csr, E, N);

    const int gather_blocks = (n2 * 16 + 255) / 256;   // 16 lanes per segment
    gather_mean_kernel<<<gather_blocks, 256, 0, stream>>>(featb, off, csr, meanb, n2);

    mfma_gemm_kernel<<<(N + 63) / 64, 256, 0, stream>>>(featb, meanb, Wb, out, N);
}